// Round 1
// baseline (35.848 us; speedup 1.0000x reference)
//
#include <hip/hip_runtime.h>

// out[p,:] = x[p,:] @ W + b  — the reference's sort/gather/scatter permutation
// cancels exactly (out_feats[inverse] with feats = x[indices] is the identity
// permutation composed with its inverse). Pure memory-bound elementwise affine.

__global__ __launch_bounds__(256) void affine3_kernel(
    const float* __restrict__ x,
    const float* __restrict__ W,
    const float* __restrict__ bias,
    float* __restrict__ out,
    long long ngroups,      // number of 4-point groups (12 floats each)
    long long npoints)      // total points P
{
    // Uniform tiny operands: 3x3 W (row-major) and b. Broadcast loads, L1-hot.
    const float w00 = W[0], w01 = W[1], w02 = W[2];
    const float w10 = W[3], w11 = W[4], w12 = W[5];
    const float w20 = W[6], w21 = W[7], w22 = W[8];
    const float b0 = bias[0], b1 = bias[1], b2 = bias[2];

    const long long tid    = (long long)blockIdx.x * blockDim.x + threadIdx.x;
    const long long stride = (long long)gridDim.x * blockDim.x;

    const float4* __restrict__ xin = reinterpret_cast<const float4*>(x);
    float4* __restrict__ xout      = reinterpret_cast<float4*>(out);

    for (long long g = tid; g < ngroups; g += stride) {
        const long long base = g * 3;
        float4 v0 = xin[base + 0];
        float4 v1 = xin[base + 1];
        float4 v2 = xin[base + 2];

        // unpack 4 points
        float p0x = v0.x, p0y = v0.y, p0z = v0.z;
        float p1x = v0.w, p1y = v1.x, p1z = v1.y;
        float p2x = v1.z, p2y = v1.w, p2z = v2.x;
        float p3x = v2.y, p3y = v2.z, p3z = v2.w;

        // affine: o_j = px*W[0][j] + py*W[1][j] + pz*W[2][j] + b[j]
        float o0x = fmaf(p0x, w00, fmaf(p0y, w10, fmaf(p0z, w20, b0)));
        float o0y = fmaf(p0x, w01, fmaf(p0y, w11, fmaf(p0z, w21, b1)));
        float o0z = fmaf(p0x, w02, fmaf(p0y, w12, fmaf(p0z, w22, b2)));

        float o1x = fmaf(p1x, w00, fmaf(p1y, w10, fmaf(p1z, w20, b0)));
        float o1y = fmaf(p1x, w01, fmaf(p1y, w11, fmaf(p1z, w21, b1)));
        float o1z = fmaf(p1x, w02, fmaf(p1y, w12, fmaf(p1z, w22, b2)));

        float o2x = fmaf(p2x, w00, fmaf(p2y, w10, fmaf(p2z, w20, b0)));
        float o2y = fmaf(p2x, w01, fmaf(p2y, w11, fmaf(p2z, w21, b1)));
        float o2z = fmaf(p2x, w02, fmaf(p2y, w12, fmaf(p2z, w22, b2)));

        float o3x = fmaf(p3x, w00, fmaf(p3y, w10, fmaf(p3z, w20, b0)));
        float o3y = fmaf(p3x, w01, fmaf(p3y, w11, fmaf(p3z, w21, b1)));
        float o3z = fmaf(p3x, w02, fmaf(p3y, w12, fmaf(p3z, w22, b2)));

        float4 r0 = make_float4(o0x, o0y, o0z, o1x);
        float4 r1 = make_float4(o1y, o1z, o2x, o2y);
        float4 r2 = make_float4(o2z, o3x, o3y, o3z);

        xout[base + 0] = r0;
        xout[base + 1] = r1;
        xout[base + 2] = r2;
    }

    // scalar tail for points not covered by 4-point groups (none for this
    // shape: P = 8388608 is divisible by 4, but keep it robust)
    for (long long p = ngroups * 4 + tid; p < npoints; p += stride) {
        float px = x[p * 3 + 0], py = x[p * 3 + 1], pz = x[p * 3 + 2];
        out[p * 3 + 0] = fmaf(px, w00, fmaf(py, w10, fmaf(pz, w20, b0)));
        out[p * 3 + 1] = fmaf(px, w01, fmaf(py, w11, fmaf(pz, w21, b1)));
        out[p * 3 + 2] = fmaf(px, w02, fmaf(py, w12, fmaf(pz, w22, b2)));
    }
}

extern "C" void kernel_launch(void* const* d_in, const int* in_sizes, int n_in,
                              void* d_out, int out_size, void* d_ws, size_t ws_size,
                              hipStream_t stream) {
    const float* x    = (const float*)d_in[0];
    const float* W    = (const float*)d_in[1];
    const float* bias = (const float*)d_in[2];
    float* out        = (float*)d_out;

    const long long n       = (long long)in_sizes[0];  // total floats in x
    const long long npoints = n / 3;
    const long long ngroups = npoints / 4;             // 4 points per thread-iter

    const int block = 256;
    long long want = (ngroups + block - 1) / block;
    int grid = (int)(want < 2048 ? (want > 0 ? want : 1) : 2048);

    affine3_kernel<<<grid, block, 0, stream>>>(x, W, bias, out, ngroups, npoints);
}